// Round 9
// baseline (146.922 us; speedup 1.0000x reference)
//
#include <hip/hip_runtime.h>
#include <hip/hip_bf16.h>

// AttentionBlock: B=4, C=64, N=4096, INTER=8 — bf16 MFMA, barrier-free main loop.
// ws: qt[4][4096][8] bf16 (q pre-scaled by log2e) | kt[4][4096][8] bf16 | vb[4][64][4096] bf16
// attn: 1 wave = 16 n-rows x 1024-m quarter; V read direct from L2 (no staging);
// swapped QK^T (mfma(K,Q)) -> lane owns 4 consecutive m -> cvt_pk P-pack; exp2 domain.

#define NPIX 4096
#define LOG2E 1.44269504088896f
typedef __attribute__((ext_vector_type(8))) short s8v;   // 8 bf16 (4 VGPR)
typedef __attribute__((ext_vector_type(4))) float f4v;   // MFMA acc

static __device__ __forceinline__ unsigned short f2bf(float f) {
    union { float f; unsigned u; } v; v.f = f;
    unsigned r = v.u + 0x7FFFu + ((v.u >> 16) & 1u);     // RNE
    return (unsigned short)(r >> 16);
}
static __device__ __forceinline__ unsigned pkbf2(float a, float b) {
    __hip_bfloat162 h = __float22bfloat162_rn(make_float2(a, b));  // a->lo, b->hi
    return *reinterpret_cast<unsigned*>(&h);
}
static __device__ __forceinline__ float fexp2(float x) {
#if __has_builtin(__builtin_amdgcn_exp2f)
    return __builtin_amdgcn_exp2f(x);
#else
    return exp2f(x);
#endif
}

// ---------------- Kernel A: qkv projection, fp32 VALU ----------------
// grid 1024 (b = bid>>8, 16-pixel tile), block 256. q-rows pre-scaled by log2e.
extern "C" __global__ void __launch_bounds__(256, 4) qkv_kernel(
    const float* __restrict__ x,
    const float* __restrict__ Wq, const float* __restrict__ bq,
    const float* __restrict__ Wk, const float* __restrict__ bk,
    const float* __restrict__ Wv, const float* __restrict__ bv,
    unsigned short* __restrict__ qt, unsigned short* __restrict__ kt,
    unsigned short* __restrict__ vb)
{
    __shared__ float xs[64][17];
    __shared__ __align__(16) float wls[80][68];
    __shared__ float bls[80];
    const int t = threadIdx.x;
    const int b = blockIdx.x >> 8, n0 = (blockIdx.x & 255) << 4;

    for (int e = t; e < 1024; e += 256) {
        int c = e >> 4, j = e & 15;
        xs[c][j] = x[((b << 6) + c) * NPIX + n0 + j];
    }
    for (int e = t; e < 5120; e += 256) {
        int row = e >> 6, cc = e & 63;
        float wv = (e < 512) ? Wq[e] * LOG2E : (e < 1024) ? Wk[e - 512] : Wv[e - 1024];
        wls[row][cc] = wv;
    }
    if (t < 80) bls[t] = (t < 8) ? bq[t] * LOG2E : (t < 16) ? bk[t - 8] : bv[t - 16];
    __syncthreads();

    const int j = t & 15, oh = t >> 4;           // rows oh*5 .. oh*5+4
    float xr[64];
#pragma unroll
    for (int c = 0; c < 64; ++c) xr[c] = xs[c][j];

    const int n = n0 + j;
#pragma unroll
    for (int r = 0; r < 5; ++r) {
        const int row = oh * 5 + r;
        float acc = bls[row];
#pragma unroll
        for (int q = 0; q < 16; ++q) {
            float4 wv = *(const float4*)&wls[row][q * 4];
            acc += wv.x * xr[4*q] + wv.y * xr[4*q+1] + wv.z * xr[4*q+2] + wv.w * xr[4*q+3];
        }
        const unsigned short h = f2bf(acc);
        if (row < 8)       qt[(b * NPIX + n) * 8 + row] = h;
        else if (row < 16) kt[(b * NPIX + n) * 8 + row - 8] = h;
        else               vb[((b << 6) + (row - 16)) * NPIX + n] = h;
    }
}

// ---------------- Kernel B: flash attention, barrier-free main loop ----------------
// grid 1024 (XCD-swizzled: b = sw>>8, 16-row group rg = sw&255), block 256 = 4 waves.
// Wave w: same 16 rows, m-quarter [w*1024, w*1024+1024). End: in-LDS O/L combine.
extern "C" __global__ void __launch_bounds__(256, 4) attn_kernel(
    const unsigned short* __restrict__ qt, const unsigned short* __restrict__ kt,
    const unsigned short* __restrict__ vb,
    const float* __restrict__ x, const float* __restrict__ gamma_p,
    float* __restrict__ out)
{
    __shared__ __align__(16) unsigned short pls[4][16][72]; // per-wave P [n][m], 144B rows
    __shared__ __align__(16) float Ored[4][64][20];         // per-wave O^T partial [c][n]
    __shared__ __align__(16) float Lr[4][16];               // per-wave L partial [n]

    const int t = threadIdx.x;
    const int w = t >> 6, lane = t & 63, g = lane >> 4, c16 = lane & 15;
    const int raw = blockIdx.x;
    const int sw = ((raw & 7) << 7) + (raw >> 3);           // XCD chunk swizzle (1024%8==0)
    const int b = sw >> 8, n0 = (sw & 255) << 4;

    const unsigned short* qtB = qt + b * NPIX * 8;
    const unsigned short* ktB = kt + b * NPIX * 8;
    const unsigned short* vbB = vb + (b << 6) * NPIX;

    // Q as B-operand: col=n=c16 (row n0+c16), k=i=g*8+j; only g==0 real (K padded 8->32)
    s8v qfr = {0,0,0,0,0,0,0,0};
    if (g == 0) qfr = *(const s8v*)(qtB + (n0 + c16) * 8);

    const int mbase = w << 10;                              // wave's m-quarter
    const unsigned short* vrow = vbB + c16 * NPIX + g * 8;  // + cs*16*NPIX + m (+32)

    f4v accO[4];
#pragma unroll
    for (int cs = 0; cs < 4; ++cs) { accO[cs][0]=0.f; accO[cs][1]=0.f; accO[cs][2]=0.f; accO[cs][3]=0.f; }
    float lsum = 0.f;

    // prologue: tile 0 K (as A-operand: row=m-local=c16, k=i; only g==0 real) and V
    s8v kf[4], vf[8];
#pragma unroll
    for (int ms = 0; ms < 4; ++ms) {
        s8v z = {0,0,0,0,0,0,0,0};
        kf[ms] = z;
        if (g == 0) kf[ms] = *(const s8v*)(ktB + (mbase + ms * 16 + c16) * 8);
    }
#pragma unroll
    for (int cs = 0; cs < 4; ++cs) {
        vf[cs*2+0] = *(const s8v*)(vrow + cs * 16 * NPIX + mbase);
        vf[cs*2+1] = *(const s8v*)(vrow + cs * 16 * NPIX + mbase + 32);
    }

    for (int ti = 0; ti < 16; ++ti) {
        const int mg = mbase + (ti << 6);

        // swapped QK^T: S^T[m][n] = K·Q ; D row = m_local = g*4+reg (+ms*16), col = n = c16
        f4v sm[4];
#pragma unroll
        for (int ms = 0; ms < 4; ++ms) {
            f4v z; z[0]=0.f; z[1]=0.f; z[2]=0.f; z[3]=0.f;
            sm[ms] = __builtin_amdgcn_mfma_f32_16x16x32_bf16(kf[ms], qfr, z, 0, 0, 0);
        }

        // refill kf for next tile (WAR after QK^T issue; latency covered by exp+PV)
        if (ti < 15) {
            const int m1 = mg + 64;
#pragma unroll
            for (int ms = 0; ms < 4; ++ms) {
                if (g == 0) kf[ms] = *(const s8v*)(ktB + (m1 + ms * 16 + c16) * 8);
            }
        }

        // p = exp2(S) (q pre-scaled by log2e; no max-subtraction, |S| small)
        // lane owns 4 consecutive m -> pack pairs, one b64 write per ms
#pragma unroll
        for (int ms = 0; ms < 4; ++ms) {
            float p0 = fexp2(sm[ms][0]), p1 = fexp2(sm[ms][1]);
            float p2 = fexp2(sm[ms][2]), p3 = fexp2(sm[ms][3]);
            lsum += (p0 + p1) + (p2 + p3);
            uint2 pk; pk.x = pkbf2(p0, p1); pk.y = pkbf2(p2, p3);
            *(uint2*)&pls[w][c16][ms * 16 + g * 4] = pk;
        }
        __builtin_amdgcn_wave_barrier();   // order cross-lane pls write -> read

        // P as B-operand: col=n=c16, k=m=g*8+j (+32)
        s8v pf0 = *(const s8v*)&pls[w][c16][g * 8];
        s8v pf1 = *(const s8v*)&pls[w][c16][32 + g * 8];

        // PV: O^T[c][n] += V[c][m]·P[m][n] ; A=V: row=c=cs*16+c16, k=m=g*8+j
#pragma unroll
        for (int cs = 0; cs < 4; ++cs) {
            accO[cs] = __builtin_amdgcn_mfma_f32_16x16x32_bf16(vf[cs*2+0], pf0, accO[cs], 0, 0, 0);
            accO[cs] = __builtin_amdgcn_mfma_f32_16x16x32_bf16(vf[cs*2+1], pf1, accO[cs], 0, 0, 0);
        }

        // refill vf for next tile (WAR after PV issue; latency covered by next QK^T+exp)
        if (ti < 15) {
            const int m1 = mg + 64;
#pragma unroll
            for (int cs = 0; cs < 4; ++cs) {
                vf[cs*2+0] = *(const s8v*)(vrow + cs * 16 * NPIX + m1);
                vf[cs*2+1] = *(const s8v*)(vrow + cs * 16 * NPIX + m1 + 32);
            }
        }
    }

    // L: reduce over g (lanes c16, c16+16, c16+32, c16+48 hold same n)
    lsum += __shfl_xor(lsum, 16);
    lsum += __shfl_xor(lsum, 32);

    // write per-wave partials
#pragma unroll
    for (int cs = 0; cs < 4; ++cs)
#pragma unroll
        for (int r = 0; r < 4; ++r)
            Ored[w][cs * 16 + g * 4 + r][c16] = accO[cs][r];
    if (g == 0) Lr[w][c16] = lsum;
    __syncthreads();

    // combine: thread t -> c = t>>2, n-local = (t&3)*4 .. +3  (float4, coalesced out)
    {
        const int c = t >> 2, nl = (t & 3) << 2;
        float4 o = *(const float4*)&Ored[0][c][nl];
        float4 o1 = *(const float4*)&Ored[1][c][nl];
        float4 o2 = *(const float4*)&Ored[2][c][nl];
        float4 o3 = *(const float4*)&Ored[3][c][nl];
        o.x += o1.x + o2.x + o3.x;  o.y += o1.y + o2.y + o3.y;
        o.z += o1.z + o2.z + o3.z;  o.w += o1.w + o2.w + o3.w;
        float4 L0 = *(const float4*)&Lr[0][nl];
        float4 L1 = *(const float4*)&Lr[1][nl];
        float4 L2 = *(const float4*)&Lr[2][nl];
        float4 L3 = *(const float4*)&Lr[3][nl];
        float4 L;
        L.x = L0.x + L1.x + L2.x + L3.x;  L.y = L0.y + L1.y + L2.y + L3.y;
        L.z = L0.z + L1.z + L2.z + L3.z;  L.w = L0.w + L1.w + L2.w + L3.w;
        const float gm = gamma_p[0];
        const int gi = ((b << 6) + c) * NPIX + n0 + nl;
        float4 xv = *(const float4*)&x[gi];
        float4 rs;
        rs.x = gm * o.x / L.x + xv.x;
        rs.y = gm * o.y / L.y + xv.y;
        rs.z = gm * o.z / L.z + xv.z;
        rs.w = gm * o.w / L.w + xv.w;
        *(float4*)&out[gi] = rs;
    }
}

extern "C" void kernel_launch(void* const* d_in, const int* in_sizes, int n_in,
                              void* d_out, int out_size, void* d_ws, size_t ws_size,
                              hipStream_t stream) {
    const float* x     = (const float*)d_in[0];
    const float* Wq    = (const float*)d_in[1];
    const float* bq    = (const float*)d_in[2];
    const float* Wk    = (const float*)d_in[3];
    const float* bk    = (const float*)d_in[4];
    const float* Wv    = (const float*)d_in[5];
    const float* bv    = (const float*)d_in[6];
    const float* gamma = (const float*)d_in[7];

    unsigned short* qt = (unsigned short*)d_ws;       // [4][4096][8]
    unsigned short* kt = qt + 4 * NPIX * 8;           // [4][4096][8]
    unsigned short* vb = kt + 4 * NPIX * 8;           // [4][64][4096]

    qkv_kernel<<<1024, 256, 0, stream>>>(x, Wq, bq, Wk, bk, Wv, bv, qt, kt, vb);
    attn_kernel<<<1024, 256, 0, stream>>>(qt, kt, vb, x, gamma, (float*)d_out);
}

// Round 11
// 112.020 us; speedup vs baseline: 1.3116x; 1.3116x over previous
//
#include <hip/hip_runtime.h>
#include <hip/hip_bf16.h>

// AttentionBlock: B=4, C=64, N=4096, INTER=8 — bf16 MFMA.
// ws: qt[4][4096][8] bf16 (pre-scaled log2e) | kt[4][4096][8] bf16 | vb[4][64][4096] bf16
// attn: round-8 skeleton (LDS-staged V per 2-wave group, in-LDS combine)
//       + swapped QK^T, cvt_pk P-pack, exp2 domain (round-9 VALU cuts).

#define NPIX 4096
#define LOG2E 1.44269504088896f
typedef __attribute__((ext_vector_type(8))) short s8v;   // 8 bf16 (4 VGPR)
typedef __attribute__((ext_vector_type(4))) float f4v;   // MFMA acc

static __device__ __forceinline__ unsigned short f2bf(float f) {
    union { float f; unsigned u; } v; v.f = f;
    unsigned r = v.u + 0x7FFFu + ((v.u >> 16) & 1u);     // RNE
    return (unsigned short)(r >> 16);
}
static __device__ __forceinline__ unsigned pkbf2(float a, float b) {
    __hip_bfloat162 h = __float22bfloat162_rn(make_float2(a, b));  // a->lo, b->hi
    return *reinterpret_cast<unsigned*>(&h);
}
static __device__ __forceinline__ float fexp2(float x) {
#if __has_builtin(__builtin_amdgcn_exp2f)
    return __builtin_amdgcn_exp2f(x);
#else
    return exp2f(x);
#endif
}

// ---------------- Kernel A: qkv projection, fp32 VALU ----------------
// grid 1024 (b = bid>>8, 16-pixel tile), block 256. q-rows pre-scaled by log2e.
extern "C" __global__ void __launch_bounds__(256, 4) qkv_kernel(
    const float* __restrict__ x,
    const float* __restrict__ Wq, const float* __restrict__ bq,
    const float* __restrict__ Wk, const float* __restrict__ bk,
    const float* __restrict__ Wv, const float* __restrict__ bv,
    unsigned short* __restrict__ qt, unsigned short* __restrict__ kt,
    unsigned short* __restrict__ vb)
{
    __shared__ float xs[64][17];
    __shared__ __align__(16) float wls[80][68];
    __shared__ float bls[80];
    const int t = threadIdx.x;
    const int b = blockIdx.x >> 8, n0 = (blockIdx.x & 255) << 4;

    for (int e = t; e < 1024; e += 256) {
        int c = e >> 4, j = e & 15;
        xs[c][j] = x[((b << 6) + c) * NPIX + n0 + j];
    }
    for (int e = t; e < 5120; e += 256) {
        int row = e >> 6, cc = e & 63;
        float wv = (e < 512) ? Wq[e] * LOG2E : (e < 1024) ? Wk[e - 512] : Wv[e - 1024];
        wls[row][cc] = wv;
    }
    if (t < 80) bls[t] = (t < 8) ? bq[t] * LOG2E : (t < 16) ? bk[t - 8] : bv[t - 16];
    __syncthreads();

    const int j = t & 15, oh = t >> 4;           // rows oh*5 .. oh*5+4
    float xr[64];
#pragma unroll
    for (int c = 0; c < 64; ++c) xr[c] = xs[c][j];

    const int n = n0 + j;
#pragma unroll
    for (int r = 0; r < 5; ++r) {
        const int row = oh * 5 + r;
        float acc = bls[row];
#pragma unroll
        for (int q = 0; q < 16; ++q) {
            float4 wv = *(const float4*)&wls[row][q * 4];
            acc += wv.x * xr[4*q] + wv.y * xr[4*q+1] + wv.z * xr[4*q+2] + wv.w * xr[4*q+3];
        }
        const unsigned short h = f2bf(acc);
        if (row < 8)       qt[(b * NPIX + n) * 8 + row] = h;
        else if (row < 16) kt[(b * NPIX + n) * 8 + row - 8] = h;
        else               vb[((b << 6) + (row - 16)) * NPIX + n] = h;
    }
}

// ---------------- Kernel B: flash attention via MFMA, in-LDS m-split ----------------
// grid 512 (XCD-swz; b = bid>>7, 32-row n-tile), block 512 = 8 waves = 4 m-groups x 2 waves.
// Group gg: m-quarter [gg*1024, +1024) as 16 tiles of 64, staged in vls[gg] (coalesced).
// Swapped QK^T (mfma(K,Q)): lane owns 4 consecutive m -> cvt_pk pack -> 4 b64 P writes.
// No-max softmax => O/L partials additive; cross-group reduce in LDS (ored aliases vls).
extern "C" __global__ void __launch_bounds__(512, 4) attn_kernel(
    const unsigned short* __restrict__ qt, const unsigned short* __restrict__ kt,
    const unsigned short* __restrict__ vb,
    const float* __restrict__ x, const float* __restrict__ gamma_p,
    float* __restrict__ out)
{
    __shared__ __align__(16) unsigned short vls[4][64][64]; // per-group V tile, XOR-swz, 32 KB
    __shared__ __align__(16) unsigned short pls[8][16][72]; // per-wave P [n][m], 144B rows
    __shared__ float Lred[4][2][16];                        // per-group L partial

    const int t = threadIdx.x;
    const int w = t >> 6, lane = t & 63, g = lane >> 4, c16 = lane & 15;
    const int gg = w >> 1, wg = w & 1;
    const int bid = ((blockIdx.x & 7) << 6) + (blockIdx.x >> 3);  // XCD chunk swizzle
    const int b = bid >> 7, n0 = (bid & 127) << 5;

    const unsigned short* qtB = qt + b * NPIX * 8;
    const unsigned short* ktB = kt + b * NPIX * 8;
    const unsigned short* vbB = vb + (b << 6) * NPIX;

    // Q as B-operand: col=n=c16 (rows n0+wg*16+c16), k=i=g*8+j; only g==0 real (K pad 8->32)
    s8v qfr = {0,0,0,0,0,0,0,0};
    if (g == 0) qfr = *(const s8v*)(qtB + (n0 + wg * 16 + c16) * 8);

    // V staging: group's 128 threads; t2 -> row vc=t2>>1, half hh=t2&1 (4 chunks of 8 bf16)
    const int t2 = t & 127;
    const int vc = t2 >> 1, hh = t2 & 1;
    const int mbase = gg << 10;                  // group's m-quarter

    f4v accO[4];
#pragma unroll
    for (int cs = 0; cs < 4; ++cs) { accO[cs][0]=0.f; accO[cs][1]=0.f; accO[cs][2]=0.f; accO[cs][3]=0.f; }
    float lsum = 0.f;

    s8v vr[4], kf[4];
    {   // prologue: group's tile 0 (V coalesced along m; K 16B/lane contiguous)
        const unsigned short* vp = vbB + vc * NPIX + mbase + hh * 32;
        vr[0] = *(const s8v*)(vp);      vr[1] = *(const s8v*)(vp + 8);
        vr[2] = *(const s8v*)(vp + 16); vr[3] = *(const s8v*)(vp + 24);
#pragma unroll
        for (int ms = 0; ms < 4; ++ms) {
            s8v z = {0,0,0,0,0,0,0,0};
            kf[ms] = z;
            if (g == 0) kf[ms] = *(const s8v*)(ktB + (mbase + ms * 16 + c16) * 8);
        }
    }

    for (int ti = 0; ti < 16; ++ti) {
        // stage current V tile (swizzled chunk pos = cj ^ (vc&7))
#pragma unroll
        for (int q = 0; q < 4; ++q) {
            const int pos = (hh * 4 + q) ^ (vc & 7);
            *(s8v*)&vls[gg][vc][pos * 8] = vr[q];
        }
        __syncthreads();

        const int m1 = mbase + ((ti + 1) << 6);
        // prefetch group's next V tile into regs (latency hides under compute)
        if (ti < 15) {
            const unsigned short* vp = vbB + vc * NPIX + m1 + hh * 32;
            vr[0] = *(const s8v*)(vp);      vr[1] = *(const s8v*)(vp + 8);
            vr[2] = *(const s8v*)(vp + 16); vr[3] = *(const s8v*)(vp + 24);
        }

        // swapped QK^T: S^T row = m_local = ms*16+g*4+reg, col = n = c16
        f4v sm[4];
#pragma unroll
        for (int ms = 0; ms < 4; ++ms) {
            f4v z; z[0]=0.f; z[1]=0.f; z[2]=0.f; z[3]=0.f;
            sm[ms] = __builtin_amdgcn_mfma_f32_16x16x32_bf16(kf[ms], qfr, z, 0, 0, 0);
        }
        // refill K for next tile (WAR after QK^T issue)
        if (ti < 15) {
#pragma unroll
            for (int ms = 0; ms < 4; ++ms)
                if (g == 0) kf[ms] = *(const s8v*)(ktB + (m1 + ms * 16 + c16) * 8);
        }

        // p = exp2(S) (q pre-scaled; no max-subtraction, |S| small)
        // lane owns 4 consecutive m -> 2 cvt_pk + one b64 write per ms
#pragma unroll
        for (int ms = 0; ms < 4; ++ms) {
            float p0 = fexp2(sm[ms][0]), p1 = fexp2(sm[ms][1]);
            float p2 = fexp2(sm[ms][2]), p3 = fexp2(sm[ms][3]);
            lsum += (p0 + p1) + (p2 + p3);
            uint2 pk; pk.x = pkbf2(p0, p1); pk.y = pkbf2(p2, p3);
            *(uint2*)&pls[w][c16][ms * 16 + g * 4] = pk;
        }
        __builtin_amdgcn_wave_barrier();   // order cross-lane pls write -> read

        // P as B-operand: col=n=c16, k=m=g*8+j (+32)
        s8v pf0 = *(const s8v*)&pls[w][c16][g * 8];
        s8v pf1 = *(const s8v*)&pls[w][c16][32 + g * 8];

        // PV: O^T[c][n] += V[c][m]·P[m][n] ; A=V from vls (swizzled), B=P
#pragma unroll
        for (int cs = 0; cs < 4; ++cs) {
            const int c = cs * 16 + c16;
            const int q0 = (g)     ^ (c16 & 7);
            const int q1 = (4 + g) ^ (c16 & 7);
            s8v vf0 = *(const s8v*)&vls[gg][c][q0 * 8];
            s8v vf1 = *(const s8v*)&vls[gg][c][q1 * 8];
            accO[cs] = __builtin_amdgcn_mfma_f32_16x16x32_bf16(vf0, pf0, accO[cs], 0, 0, 0);
            accO[cs] = __builtin_amdgcn_mfma_f32_16x16x32_bf16(vf1, pf1, accO[cs], 0, 0, 0);
        }
        __syncthreads();                   // protect vls before next stage
    }

    // L partial: reduce over g (lanes with same c16 share n)
    lsum += __shfl_xor(lsum, 16);
    lsum += __shfl_xor(lsum, 32);
    if (g == 0) Lred[gg][wg][c16] = lsum;

    // cross-group O reduce (tree); ored aliases vls (dead after loop's final barrier)
    float (*ored)[128][17] = reinterpret_cast<float(*)[128][17]>(&vls[0][0][0]);
    const int s2 = t & 127;
    if (gg >= 2) {
#pragma unroll
        for (int cs = 0; cs < 4; ++cs)
#pragma unroll
            for (int r = 0; r < 4; ++r) ored[gg - 2][s2][cs * 4 + r] = accO[cs][r];
    }
    __syncthreads();
    if (gg < 2) {
#pragma unroll
        for (int cs = 0; cs < 4; ++cs)
#pragma unroll
            for (int r = 0; r < 4; ++r) accO[cs][r] += ored[gg][s2][cs * 4 + r];
    }
    __syncthreads();
    if (gg == 1) {
#pragma unroll
        for (int cs = 0; cs < 4; ++cs)
#pragma unroll
            for (int r = 0; r < 4; ++r) ored[0][s2][cs * 4 + r] = accO[cs][r];
    }
    __syncthreads();
    if (gg == 0) {
#pragma unroll
        for (int cs = 0; cs < 4; ++cs)
#pragma unroll
            for (int r = 0; r < 4; ++r) accO[cs][r] += ored[0][s2][cs * 4 + r];

        const float L = Lred[0][wg][c16] + Lred[1][wg][c16]
                      + Lred[2][wg][c16] + Lred[3][wg][c16];
        const float inv = 1.0f / L;
        const float gm = gamma_p[0];
        const int n = n0 + wg * 16 + c16;
#pragma unroll
        for (int cs = 0; cs < 4; ++cs)
#pragma unroll
            for (int r = 0; r < 4; ++r) {
                const int c = cs * 16 + g * 4 + r;
                const int gi = ((b << 6) + c) * NPIX + n;
                out[gi] = gm * (accO[cs][r] * inv) + x[gi];
            }
    }
}

extern "C" void kernel_launch(void* const* d_in, const int* in_sizes, int n_in,
                              void* d_out, int out_size, void* d_ws, size_t ws_size,
                              hipStream_t stream) {
    const float* x     = (const float*)d_in[0];
    const float* Wq    = (const float*)d_in[1];
    const float* bq    = (const float*)d_in[2];
    const float* Wk    = (const float*)d_in[3];
    const float* bk    = (const float*)d_in[4];
    const float* Wv    = (const float*)d_in[5];
    const float* bv    = (const float*)d_in[6];
    const float* gamma = (const float*)d_in[7];

    unsigned short* qt = (unsigned short*)d_ws;       // [4][4096][8]
    unsigned short* kt = qt + 4 * NPIX * 8;           // [4][4096][8]
    unsigned short* vb = kt + 4 * NPIX * 8;           // [4][64][4096]

    qkv_kernel<<<1024, 256, 0, stream>>>(x, Wq, bq, Wk, bk, Wv, bv, qt, kt, vb);
    attn_kernel<<<512, 512, 0, stream>>>(qt, kt, vb, x, gamma, (float*)d_out);
}

// Round 12
// 111.668 us; speedup vs baseline: 1.3157x; 1.0031x over previous
//
#include <hip/hip_runtime.h>
#include <hip/hip_bf16.h>

// AttentionBlock: B=4, C=64, N=4096, INTER=8 — bf16 MFMA, K=16 shapes, in-register P.
// ws: qt[4][4096][8] bf16 (pre-scaled log2e) | kt[4][4096][8] bf16 | vb[4][64][4096] bf16
// attn: 8-wave blocks, 4 m-groups x 2 waves; V double-buffered in LDS (1 barrier/tile);
// swapped QK^T (mfma(K,Q), 16x16x16) -> P fragment is lane-local (cvt_pk, no LDS).

#define NPIX 4096
#define LOG2E 1.44269504088896f
typedef __attribute__((ext_vector_type(8))) short s8v;   // 8 bf16 (4 VGPR)
typedef __attribute__((ext_vector_type(4))) short s4v;   // 4 bf16 (2 VGPR)
typedef __attribute__((ext_vector_type(4))) float f4v;   // MFMA acc

static __device__ __forceinline__ unsigned short f2bf(float f) {
    union { float f; unsigned u; } v; v.f = f;
    unsigned r = v.u + 0x7FFFu + ((v.u >> 16) & 1u);     // RNE
    return (unsigned short)(r >> 16);
}
static __device__ __forceinline__ unsigned pkbf2(float a, float b) {
    __hip_bfloat162 h = __float22bfloat162_rn(make_float2(a, b));  // a->lo, b->hi
    return *reinterpret_cast<unsigned*>(&h);
}
static __device__ __forceinline__ float fexp2(float x) {
#if __has_builtin(__builtin_amdgcn_exp2f)
    return __builtin_amdgcn_exp2f(x);
#else
    return exp2f(x);
#endif
}

// K=16 bf16 MFMA; fallback: zero-padded K=32 embedding (k=g*8+j, j<4 real on BOTH
// operands -> contraction over the same embedded indices, mathematically identical).
static __device__ __forceinline__ f4v mfma16(s4v a, s4v b, f4v c) {
#if __has_builtin(__builtin_amdgcn_mfma_f32_16x16x16bf16_1k)
    return __builtin_amdgcn_mfma_f32_16x16x16bf16_1k(a, b, c, 0, 0, 0);
#else
    s8v a8 = {a[0], a[1], a[2], a[3], 0, 0, 0, 0};
    s8v b8 = {b[0], b[1], b[2], b[3], 0, 0, 0, 0};
    return __builtin_amdgcn_mfma_f32_16x16x32_bf16(a8, b8, c, 0, 0, 0);
#endif
}

// ---------------- Kernel A: qkv projection, fp32 VALU ----------------
// grid 1024 (b = bid>>8, 16-pixel tile), block 256. q-rows pre-scaled by log2e.
extern "C" __global__ void __launch_bounds__(256, 4) qkv_kernel(
    const float* __restrict__ x,
    const float* __restrict__ Wq, const float* __restrict__ bq,
    const float* __restrict__ Wk, const float* __restrict__ bk,
    const float* __restrict__ Wv, const float* __restrict__ bv,
    unsigned short* __restrict__ qt, unsigned short* __restrict__ kt,
    unsigned short* __restrict__ vb)
{
    __shared__ float xs[64][17];
    __shared__ __align__(16) float wls[80][68];
    __shared__ float bls[80];
    const int t = threadIdx.x;
    const int b = blockIdx.x >> 8, n0 = (blockIdx.x & 255) << 4;

    for (int e = t; e < 1024; e += 256) {
        int c = e >> 4, j = e & 15;
        xs[c][j] = x[((b << 6) + c) * NPIX + n0 + j];
    }
    for (int e = t; e < 5120; e += 256) {
        int row = e >> 6, cc = e & 63;
        float wv = (e < 512) ? Wq[e] * LOG2E : (e < 1024) ? Wk[e - 512] : Wv[e - 1024];
        wls[row][cc] = wv;
    }
    if (t < 80) bls[t] = (t < 8) ? bq[t] * LOG2E : (t < 16) ? bk[t - 8] : bv[t - 16];
    __syncthreads();

    const int j = t & 15, oh = t >> 4;           // rows oh*5 .. oh*5+4
    float xr[64];
#pragma unroll
    for (int c = 0; c < 64; ++c) xr[c] = xs[c][j];

    const int n = n0 + j;
#pragma unroll
    for (int r = 0; r < 5; ++r) {
        const int row = oh * 5 + r;
        float acc = bls[row];
#pragma unroll
        for (int q = 0; q < 16; ++q) {
            float4 wv = *(const float4*)&wls[row][q * 4];
            acc += wv.x * xr[4*q] + wv.y * xr[4*q+1] + wv.z * xr[4*q+2] + wv.w * xr[4*q+3];
        }
        const unsigned short h = f2bf(acc);
        if (row < 8)       qt[(b * NPIX + n) * 8 + row] = h;
        else if (row < 16) kt[(b * NPIX + n) * 8 + row - 8] = h;
        else               vb[((b << 6) + (row - 16)) * NPIX + n] = h;
    }
}

// ---------------- Kernel B: flash attention, K=16 MFMA, 1 barrier/tile ----------------
// grid 512 (XCD-swz; b = bid>>7, 32-row n-tile), block 512 = 8 waves = 4 m-groups x 2.
// Group gg: m-quarter [gg*1024,+1024) as 16 tiles of 64, double-buffered in vls.
// Per tile: QK^T = 4x mfma16(K,Q) (K pad 8->16); P = exp2(S) packed IN-REGISTER
// (QK^T out row=g*4+r == A/B-frag k=g*4+j); PV = 16x mfma16(V,P). No pls, no wave_barrier.
extern "C" __global__ void __launch_bounds__(512, 4) attn_kernel(
    const unsigned short* __restrict__ qt, const unsigned short* __restrict__ kt,
    const unsigned short* __restrict__ vb,
    const float* __restrict__ x, const float* __restrict__ gamma_p,
    float* __restrict__ out)
{
    __shared__ __align__(16) unsigned short vls[2][4][64][64]; // dbuf V tiles, XOR-swz, 64 KB
    __shared__ float Lred[4][2][16];                           // per-group L partial

    const int t = threadIdx.x;
    const int w = t >> 6, lane = t & 63, g = lane >> 4, c16 = lane & 15;
    const int gg = w >> 1, wg = w & 1;
    const int bid = ((blockIdx.x & 7) << 6) + (blockIdx.x >> 3);  // XCD chunk swizzle
    const int b = bid >> 7, n0 = (bid & 127) << 5;

    const unsigned short* qtB = qt + b * NPIX * 8;
    const unsigned short* ktB = kt + b * NPIX * 8;
    const unsigned short* vbB = vb + (b << 6) * NPIX;

    // Q B-frag (K=16): col=n=c16 (row n0+wg*16+c16), k=g*4+j; real k<8 -> g<2
    s4v qfr = {0, 0, 0, 0};
    if (g < 2) qfr = *(const s4v*)(qtB + (n0 + wg * 16 + c16) * 8 + g * 4);

    // V staging: group's 128 threads; t2 -> row vc=t2>>1, half hh=t2&1 (4 chunks of 8)
    const int t2 = t & 127;
    const int vc = t2 >> 1, hh = t2 & 1;
    const int mbase = gg << 10;                  // group's m-quarter

    f4v accO[4];
#pragma unroll
    for (int cs = 0; cs < 4; ++cs) { accO[cs][0]=0.f; accO[cs][1]=0.f; accO[cs][2]=0.f; accO[cs][3]=0.f; }
    float lsum = 0.f;

    s8v vr[4];
    s4v kf[4], kfn[4];
    {   // prologue: tile 0 V + K (A-frag K=16: row=m_local=ms*16+c16, k=g*4+j, g<2 real)
        const unsigned short* vp = vbB + vc * NPIX + mbase + hh * 32;
        vr[0] = *(const s8v*)(vp);      vr[1] = *(const s8v*)(vp + 8);
        vr[2] = *(const s8v*)(vp + 16); vr[3] = *(const s8v*)(vp + 24);
#pragma unroll
        for (int ms = 0; ms < 4; ++ms) {
            s4v z = {0, 0, 0, 0};
            kf[ms] = z;
            if (g < 2) kf[ms] = *(const s4v*)(ktB + (mbase + ms * 16 + c16) * 8 + g * 4);
        }
        // stage tile 0 into buf 0 (swizzled chunk pos = c_k ^ (row&7))
#pragma unroll
        for (int q = 0; q < 4; ++q) {
            const int pos = (hh * 4 + q) ^ (vc & 7);
            *(s8v*)&vls[0][gg][vc][pos * 8] = vr[q];
        }
    }
    __syncthreads();

    int cur = 0;
    for (int ti = 0; ti < 16; ++ti) {
        const int m1 = mbase + ((ti + 1) << 6);
        // prefetch next tile globals (latency hides under this tile's compute)
        if (ti < 15) {
            const unsigned short* vp = vbB + vc * NPIX + m1 + hh * 32;
            vr[0] = *(const s8v*)(vp);      vr[1] = *(const s8v*)(vp + 8);
            vr[2] = *(const s8v*)(vp + 16); vr[3] = *(const s8v*)(vp + 24);
#pragma unroll
            for (int ms = 0; ms < 4; ++ms) {
                s4v z = {0, 0, 0, 0};
                kfn[ms] = z;
                if (g < 2) kfn[ms] = *(const s4v*)(ktB + (m1 + ms * 16 + c16) * 8 + g * 4);
            }
        }

        // swapped QK^T (K=16): S^T row = m_local = ms*16+g*4+reg, col = n = c16
        f4v sm[4];
#pragma unroll
        for (int ms = 0; ms < 4; ++ms) {
            f4v z; z[0]=0.f; z[1]=0.f; z[2]=0.f; z[3]=0.f;
            sm[ms] = mfma16(kf[ms], qfr, z);
        }

        // p = exp2(S); pack lane-local P fragment (row g*4+r == frag k=g*4+j: no LDS!)
        s4v pf[4];
#pragma unroll
        for (int ms = 0; ms < 4; ++ms) {
            float p0 = fexp2(sm[ms][0]), p1 = fexp2(sm[ms][1]);
            float p2 = fexp2(sm[ms][2]), p3 = fexp2(sm[ms][3]);
            lsum += (p0 + p1) + (p2 + p3);
            union { uint2 u; s4v v; } pu;
            pu.u.x = pkbf2(p0, p1); pu.u.y = pkbf2(p2, p3);
            pf[ms] = pu.v;
        }

        // PV (K=16 x16): O^T[c][n] += V[c][m]·P[m][n]; vf = b64 from swizzled vls
#pragma unroll
        for (int cs = 0; cs < 4; ++cs) {
            const int c = cs * 16 + c16;
#pragma unroll
            for (int ms = 0; ms < 4; ++ms) {
                const int pos = (2 * ms + (g >> 1)) ^ (c & 7);
                s4v vf = *(const s4v*)&vls[cur][gg][c][pos * 8 + (g & 1) * 4];
                accO[cs] = mfma16(vf, pf[ms], accO[cs]);
            }
        }

        // stage next tile into the other buffer (no conflict with cur reads)
        if (ti < 15) {
#pragma unroll
            for (int q = 0; q < 4; ++q) {
                const int pos = (hh * 4 + q) ^ (vc & 7);
                *(s8v*)&vls[cur ^ 1][gg][vc][pos * 8] = vr[q];
            }
#pragma unroll
            for (int ms = 0; ms < 4; ++ms) kf[ms] = kfn[ms];
        }
        __syncthreads();                  // one barrier per tile
        cur ^= 1;
    }

    // L partial: reduce over g (lanes with same c16 share n)
    lsum += __shfl_xor(lsum, 16);
    lsum += __shfl_xor(lsum, 32);
    if (g == 0) Lred[gg][wg][c16] = lsum;

    // cross-group O reduce (tree); ored aliases vls (dead after final barrier)
    float (*ored)[128][17] = reinterpret_cast<float(*)[128][17]>(&vls[0][0][0][0]);
    const int s2 = t & 127;
    if (gg >= 2) {
#pragma unroll
        for (int cs = 0; cs < 4; ++cs)
#pragma unroll
            for (int r = 0; r < 4; ++r) ored[gg - 2][s2][cs * 4 + r] = accO[cs][r];
    }
    __syncthreads();
    if (gg < 2) {
#pragma unroll
        for (int cs = 0; cs < 4; ++cs)
#pragma unroll
            for (int r = 0; r < 4; ++r) accO[cs][r] += ored[gg][s2][cs * 4 + r];
    }
    __syncthreads();
    if (gg == 1) {
#pragma unroll
        for (int cs = 0; cs < 4; ++cs)
#pragma unroll
            for (int r = 0; r < 4; ++r) ored[0][s2][cs * 4 + r] = accO[cs][r];
    }
    __syncthreads();
    if (gg == 0) {
#pragma unroll
        for (int cs = 0; cs < 4; ++cs)
#pragma unroll
            for (int r = 0; r < 4; ++r) accO[cs][r] += ored[0][s2][cs * 4 + r];

        const float L = Lred[0][wg][c16] + Lred[1][wg][c16]
                      + Lred[2][wg][c16] + Lred[3][wg][c16];
        const float inv = 1.0f / L;
        const float gm = gamma_p[0];
        const int n = n0 + wg * 16 + c16;
#pragma unroll
        for (int cs = 0; cs < 4; ++cs)
#pragma unroll
            for (int r = 0; r < 4; ++r) {
                const int c = cs * 16 + g * 4 + r;
                const int gi = ((b << 6) + c) * NPIX + n;
                out[gi] = gm * (accO[cs][r] * inv) + x[gi];
            }
    }
}

extern "C" void kernel_launch(void* const* d_in, const int* in_sizes, int n_in,
                              void* d_out, int out_size, void* d_ws, size_t ws_size,
                              hipStream_t stream) {
    const float* x     = (const float*)d_in[0];
    const float* Wq    = (const float*)d_in[1];
    const float* bq    = (const float*)d_in[2];
    const float* Wk    = (const float*)d_in[3];
    const float* bk    = (const float*)d_in[4];
    const float* Wv    = (const float*)d_in[5];
    const float* bv    = (const float*)d_in[6];
    const float* gamma = (const float*)d_in[7];

    unsigned short* qt = (unsigned short*)d_ws;       // [4][4096][8]
    unsigned short* kt = qt + 4 * NPIX * 8;           // [4][4096][8]
    unsigned short* vb = kt + 4 * NPIX * 8;           // [4][64][4096]

    qkv_kernel<<<1024, 256, 0, stream>>>(x, Wq, bq, Wk, bk, Wv, bv, qt, kt, vb);
    attn_kernel<<<512, 512, 0, stream>>>(qt, kt, vb, x, gamma, (float*)d_out);
}

// Round 14
// 109.325 us; speedup vs baseline: 1.3439x; 1.0214x over previous
//
#include <hip/hip_runtime.h>
#include <hip/hip_bf16.h>

// AttentionBlock: B=4, C=64, N=4096, INTER=8 — bf16 MFMA, K=16, in-register P,
// V staged via global_load_lds (pre-swizzled source, zero ds_write / zero staging VGPRs).
// ws: qt[4][4096][8] bf16 (pre-scaled log2e) | kt[4][4096][8] bf16 | vb[4][64][4096] bf16

#define NPIX 4096
#define LOG2E 1.44269504088896f
#define AS1 __attribute__((address_space(1)))
#define AS3 __attribute__((address_space(3)))
typedef __attribute__((ext_vector_type(8))) short s8v;   // 8 bf16 (4 VGPR)
typedef __attribute__((ext_vector_type(4))) short s4v;   // 4 bf16 (2 VGPR)
typedef __attribute__((ext_vector_type(4))) float f4v;   // MFMA acc

static __device__ __forceinline__ unsigned short f2bf(float f) {
    union { float f; unsigned u; } v; v.f = f;
    unsigned r = v.u + 0x7FFFu + ((v.u >> 16) & 1u);     // RNE
    return (unsigned short)(r >> 16);
}
static __device__ __forceinline__ unsigned pkbf2(float a, float b) {
    __hip_bfloat162 h = __float22bfloat162_rn(make_float2(a, b));  // a->lo, b->hi
    return *reinterpret_cast<unsigned*>(&h);
}
static __device__ __forceinline__ float fexp2(float x) {
#if __has_builtin(__builtin_amdgcn_exp2f)
    return __builtin_amdgcn_exp2f(x);
#else
    return exp2f(x);
#endif
}
// K=16 bf16 MFMA; fallback: zero-padded K=32 embedding (identical contraction).
static __device__ __forceinline__ f4v mfma16(s4v a, s4v b, f4v c) {
#if __has_builtin(__builtin_amdgcn_mfma_f32_16x16x16bf16_1k)
    return __builtin_amdgcn_mfma_f32_16x16x16bf16_1k(a, b, c, 0, 0, 0);
#else
    s8v a8 = {a[0], a[1], a[2], a[3], 0, 0, 0, 0};
    s8v b8 = {b[0], b[1], b[2], b[3], 0, 0, 0, 0};
    return __builtin_amdgcn_mfma_f32_16x16x32_bf16(a8, b8, c, 0, 0, 0);
#endif
}

// ---------------- Kernel A: qkv projection, fp32 VALU ----------------
// grid 1024 (b = bid>>8, 16-pixel tile), block 256. q-rows pre-scaled by log2e.
extern "C" __global__ void __launch_bounds__(256, 4) qkv_kernel(
    const float* __restrict__ x,
    const float* __restrict__ Wq, const float* __restrict__ bq,
    const float* __restrict__ Wk, const float* __restrict__ bk,
    const float* __restrict__ Wv, const float* __restrict__ bv,
    unsigned short* __restrict__ qt, unsigned short* __restrict__ kt,
    unsigned short* __restrict__ vb)
{
    __shared__ float xs[64][17];
    __shared__ __align__(16) float wls[80][68];
    __shared__ float bls[80];
    const int t = threadIdx.x;
    const int b = blockIdx.x >> 8, n0 = (blockIdx.x & 255) << 4;

    for (int e = t; e < 1024; e += 256) {
        int c = e >> 4, j = e & 15;
        xs[c][j] = x[((b << 6) + c) * NPIX + n0 + j];
    }
    for (int e = t; e < 5120; e += 256) {
        int row = e >> 6, cc = e & 63;
        float wv = (e < 512) ? Wq[e] * LOG2E : (e < 1024) ? Wk[e - 512] : Wv[e - 1024];
        wls[row][cc] = wv;
    }
    if (t < 80) bls[t] = (t < 8) ? bq[t] * LOG2E : (t < 16) ? bk[t - 8] : bv[t - 16];
    __syncthreads();

    const int j = t & 15, oh = t >> 4;           // rows oh*5 .. oh*5+4
    float xr[64];
#pragma unroll
    for (int c = 0; c < 64; ++c) xr[c] = xs[c][j];

    const int n = n0 + j;
#pragma unroll
    for (int r = 0; r < 5; ++r) {
        const int row = oh * 5 + r;
        float acc = bls[row];
#pragma unroll
        for (int q = 0; q < 16; ++q) {
            float4 wv = *(const float4*)&wls[row][q * 4];
            acc += wv.x * xr[4*q] + wv.y * xr[4*q+1] + wv.z * xr[4*q+2] + wv.w * xr[4*q+3];
        }
        const unsigned short h = f2bf(acc);
        if (row < 8)       qt[(b * NPIX + n) * 8 + row] = h;
        else if (row < 16) kt[(b * NPIX + n) * 8 + row - 8] = h;
        else               vb[((b << 6) + (row - 16)) * NPIX + n] = h;
    }
}

// ---------------- Kernel B: flash attention, gl_lds V staging, 1 barrier/tile ----------------
// grid 512 (XCD-swz; b = bid>>7, 32-row n-tile), block 512 = 8 waves = 4 m-groups x 2.
// Group gg: m-quarter [gg*1024,+1024) as 16 tiles of 64, double-buffered in vls via
// global_load_lds with pre-swizzled SOURCE (dst chunk cd holds src chunk cd^(row&7)).
// QK^T = 4x mfma16(K,Q); P packed in-register; PV = 16x mfma16(V,P).
extern "C" __global__ void __launch_bounds__(512, 4) attn_kernel(
    const unsigned short* __restrict__ qt, const unsigned short* __restrict__ kt,
    const unsigned short* __restrict__ vb,
    const float* __restrict__ x, const float* __restrict__ gamma_p,
    float* __restrict__ out)
{
    __shared__ __align__(16) unsigned short vls[2][4][64][64]; // dbuf V tiles, swz, 64 KB
    __shared__ float Lred[4][2][16];                           // per-group L partial

    const int t = threadIdx.x;
    const int w = t >> 6, lane = t & 63, g = lane >> 4, c16 = lane & 15;
    const int gg = w >> 1, wg = w & 1;
    const int bid = ((blockIdx.x & 7) << 6) + (blockIdx.x >> 3);  // XCD chunk swizzle
    const int b = bid >> 7, n0 = (bid & 127) << 5;

    const unsigned short* qtB = qt + b * NPIX * 8;
    const unsigned short* ktB = kt + b * NPIX * 8;
    const unsigned short* vbB = vb + (b << 6) * NPIX;

    // Q B-frag (K=16): col=n=c16 (row n0+wg*16+c16), k=g*4+j; real k<8 -> g<2
    s4v qfr = {0, 0, 0, 0};
    if (g < 2) qfr = *(const s4v*)(qtB + (n0 + wg * 16 + c16) * 8 + g * 4);

    // gl_lds staging geometry: wave wg stages rows wg*32 + s*8 .. +7 (s=0..3) of the
    // group's tile. Lane l -> row (wg*32 + s*8 + (l>>3)), dst chunk l&7; src chunk
    // pre-swizzled: (l&7) ^ (row&7) = (l&7) ^ (l>>3)   [row&7 == l>>3].
    const int srow = (wg << 5) + (lane >> 3);
    const int schk = (lane & 7) ^ (lane >> 3);
    const unsigned short* sgp = vbB + srow * NPIX + schk * 8;   // + m0 + s*8*NPIX
    const int mbase = gg << 10;                                 // group's m-quarter

    f4v accO[4];
#pragma unroll
    for (int cs = 0; cs < 4; ++cs) { accO[cs][0]=0.f; accO[cs][1]=0.f; accO[cs][2]=0.f; accO[cs][3]=0.f; }
    float lsum = 0.f;

    s4v kf[4], kfn[4];
    {   // prologue: stage tile 0 into buf0; load K tile 0 (A-frag: row=m_local, k=g*4+j, g<2)
#pragma unroll
        for (int s = 0; s < 4; ++s) {
            const unsigned short* gp = sgp + mbase + s * 8 * NPIX;
            void* lp = (void*)&vls[0][gg][(wg << 5) + s * 8][0];
            __builtin_amdgcn_global_load_lds((AS1 const void*)gp, (AS3 void*)lp, 16, 0, 0);
        }
#pragma unroll
        for (int ms = 0; ms < 4; ++ms) {
            s4v z = {0, 0, 0, 0};
            kf[ms] = z;
            if (g < 2) kf[ms] = *(const s4v*)(ktB + (mbase + ms * 16 + c16) * 8 + g * 4);
        }
    }
    __syncthreads();   // drains gl_lds (vmcnt 0) -> buf0 ready

    int cur = 0;
    for (int ti = 0; ti < 16; ++ti) {
        // issue next tile's staging FIRST (latency hides under this tile's compute)
        if (ti < 15) {
            const int m1 = mbase + ((ti + 1) << 6);
#pragma unroll
            for (int s = 0; s < 4; ++s) {
                const unsigned short* gp = sgp + m1 + s * 8 * NPIX;
                void* lp = (void*)&vls[cur ^ 1][gg][(wg << 5) + s * 8][0];
                __builtin_amdgcn_global_load_lds((AS1 const void*)gp, (AS3 void*)lp, 16, 0, 0);
            }
#pragma unroll
            for (int ms = 0; ms < 4; ++ms) {
                s4v z = {0, 0, 0, 0};
                kfn[ms] = z;
                if (g < 2) kfn[ms] = *(const s4v*)(ktB + (m1 + ms * 16 + c16) * 8 + g * 4);
            }
        }

        // swapped QK^T (K=16): S^T row = m_local = ms*16+g*4+reg, col = n = c16
        f4v sm[4];
#pragma unroll
        for (int ms = 0; ms < 4; ++ms) {
            f4v z; z[0]=0.f; z[1]=0.f; z[2]=0.f; z[3]=0.f;
            sm[ms] = mfma16(kf[ms], qfr, z);
        }

        // p = exp2(S); pack lane-local P fragment (row g*4+r == frag k=g*4+j)
        s4v pf[4];
#pragma unroll
        for (int ms = 0; ms < 4; ++ms) {
            float p0 = fexp2(sm[ms][0]), p1 = fexp2(sm[ms][1]);
            float p2 = fexp2(sm[ms][2]), p3 = fexp2(sm[ms][3]);
            lsum += (p0 + p1) + (p2 + p3);
            union { uint2 u; s4v v; } pu;
            pu.u.x = pkbf2(p0, p1); pu.u.y = pkbf2(p2, p3);
            pf[ms] = pu.v;
        }

        // PV (K=16 x16): O^T[c][n] += V[c][m]·P[m][n]; vf from swizzled vls
#pragma unroll
        for (int cs = 0; cs < 4; ++cs) {
            const int c = cs * 16 + c16;
#pragma unroll
            for (int ms = 0; ms < 4; ++ms) {
                const int pos = (2 * ms + (g >> 1)) ^ (c & 7);
                s4v vf = *(const s4v*)&vls[cur][gg][c][pos * 8 + (g & 1) * 4];
                accO[cs] = mfma16(vf, pf[ms], accO[cs]);
            }
        }

#pragma unroll
        for (int ms = 0; ms < 4; ++ms) kf[ms] = kfn[ms];
        __syncthreads();      // one barrier/tile; drains next-tile gl_lds
        cur ^= 1;
    }

    // L partial: reduce over g (lanes with same c16 share n)
    lsum += __shfl_xor(lsum, 16);
    lsum += __shfl_xor(lsum, 32);
    if (g == 0) Lred[gg][wg][c16] = lsum;

    // cross-group O reduce (tree); ored aliases vls (dead after final barrier)
    float (*ored)[128][17] = reinterpret_cast<float(*)[128][17]>(&vls[0][0][0][0]);
    const int s2 = t & 127;
    if (gg >= 2) {
#pragma unroll
        for (int cs = 0; cs < 4; ++cs)
#pragma unroll
            for (int r = 0; r < 4; ++r) ored[gg - 2][s2][cs * 4 + r] = accO[cs][r];
    }
    __syncthreads();
    if (gg < 2) {
#pragma unroll
        for (int cs = 0; cs < 4; ++cs)
#pragma unroll
            for (int r = 0; r < 4; ++r) accO[cs][r] += ored[gg][s2][cs * 4 + r];
    }
    __syncthreads();
    if (gg == 1) {
#pragma unroll
        for (int cs = 0; cs < 4; ++cs)
#pragma unroll
            for (int r = 0; r < 4; ++r) ored[0][s2][cs * 4 + r] = accO[cs][r];
    }
    __syncthreads();
    if (gg == 0) {
#pragma unroll
        for (int cs = 0; cs < 4; ++cs)
#pragma unroll
            for (int r = 0; r < 4; ++r) accO[cs][r] += ored[0][s2][cs * 4 + r];

        const float L = Lred[0][wg][c16] + Lred[1][wg][c16]
                      + Lred[2][wg][c16] + Lred[3][wg][c16];
        const float inv = 1.0f / L;
        const float gm = gamma_p[0];
        const int n = n0 + wg * 16 + c16;
#pragma unroll
        for (int cs = 0; cs < 4; ++cs)
#pragma unroll
            for (int r = 0; r < 4; ++r) {
                const int c = cs * 16 + g * 4 + r;
                const int gi = ((b << 6) + c) * NPIX + n;
                out[gi] = gm * (accO[cs][r] * inv) + x[gi];
            }
    }
}

extern "C" void kernel_launch(void* const* d_in, const int* in_sizes, int n_in,
                              void* d_out, int out_size, void* d_ws, size_t ws_size,
                              hipStream_t stream) {
    const float* x     = (const float*)d_in[0];
    const float* Wq    = (const float*)d_in[1];
    const float* bq    = (const float*)d_in[2];
    const float* Wk    = (const float*)d_in[3];
    const float* bk    = (const float*)d_in[4];
    const float* Wv    = (const float*)d_in[5];
    const float* bv    = (const float*)d_in[6];
    const float* gamma = (const float*)d_in[7];

    unsigned short* qt = (unsigned short*)d_ws;       // [4][4096][8]
    unsigned short* kt = qt + 4 * NPIX * 8;           // [4][4096][8]
    unsigned short* vb = kt + 4 * NPIX * 8;           // [4][64][4096]

    qkv_kernel<<<1024, 256, 0, stream>>>(x, Wq, bq, Wk, bk, Wv, bv, qt, kt, vb);
    attn_kernel<<<512, 512, 0, stream>>>(qt, kt, vb, x, gamma, (float*)d_out);
}